// Round 6
// baseline (266.456 us; speedup 1.0000x reference)
//
#include <hip/hip_runtime.h>

typedef __attribute__((ext_vector_type(8))) short short8;   // 8 bf16 = 4 VGPRs
typedef __attribute__((ext_vector_type(4))) float float4v;  // 4 fp32

static __device__ inline short f2bf(float f) {
    union { float f; unsigned u; } v; v.f = f;
    unsigned u = v.u;
    u += 0x7fffu + ((u >> 16) & 1u);   // round-to-nearest-even
    return (short)(u >> 16);
}

// Setup: Wt[n][k] = W[k][n] in bf16, row-major stride 128, written to d_ws.
// W[k][n] = [[cos, sin], [-sin, cos]] (cos/sin symmetric 64x64, scaled 1/64).
__global__ __launch_bounds__(256)
void build_wt(const float* __restrict__ cosk, const float* __restrict__ sink,
              short* __restrict__ wt)
{
    const int idx = blockIdx.x * 256 + threadIdx.x;  // 0..16383
    const int n = idx >> 7, k = idx & 127;
    const int nn = n & 63, km = k & 63;
    float v;
    if (n < 64) v = (k < 64) ? cosk[n * 64 + k] : -sink[n * 64 + km];
    else        v = (k < 64) ? sink[nn * 64 + k] : cosk[nn * 64 + km];
    wt[idx] = f2bf(v);
}

// async 16B global->LDS (wave-uniform LDS base + lane*16, per-lane global src)
typedef __attribute__((address_space(1))) const unsigned g_u32;
typedef __attribute__((address_space(3))) unsigned l_u32;
__device__ static inline void gload_lds16(void* l, const void* g) {
    __builtin_amdgcn_global_load_lds((g_u32*)g, (l_u32*)l, 16, 0, 0);
}

// Main: out[b,n'] = sum_k A[b,k] * W[k,n'].
// 512 persistent blocks x 4 waves; each wave owns 16 batches/tile, 8 tiles,
// double-buffered 8KB LDS regions, PER-WAVE self-staging => no barriers.
// LDS layout (both in and out tiles): row r (batch) = 512B, chunk c (16B)
// stored at position c ^ (r&7)  [XOR swizzle; involution].
// Staging: lane l of instr i covers LDS chunk i*64+l (linear) from the
// inverse-swizzled global source => coalesced 1KB per instruction.
// Compute: operand-swapped 16x16x32 MFMA (weights on M), lane (q,m) holds
// out[b0+m][nt*16+q*4 .. +3]; result staged to LDS, drained as dense 1KB
// contiguous stores.
__global__ __launch_bounds__(256, 2)
void ofdm_idft_kernel(const float* __restrict__ eq,
                      const short* __restrict__ wt,
                      float* __restrict__ out)
{
    extern __shared__ char lds[];   // 65536 B: 2 buffers x 4 waves x 8KB
    const int lane = threadIdx.x & 63;
    const int wave = threadIdx.x >> 6;
    const int m    = lane & 15;   // batch row within wave-tile / wt row sel
    const int q    = lane >> 4;   // quad
    const int half = lane >> 5;   // staging: row parity
    const int pos  = lane & 31;   // staging: chunk within row

    char* buf0 = lds + wave * 8192;
    char* buf1 = lds + 32768 + wave * 8192;

    const int wid = blockIdx.x * 4 + wave;   // 0..2047
    const unsigned long long PMASK =
        (1ull << 11) | (1ull << 25) | (1ull << 39) | (1ull << 53);

    // stage tile 'it' (16 batches) into buffer B: 8 x global_load_lds_dwordx4
    auto STAGE = [&](char* B, int it) {
        const size_t tb = (size_t)(it * 2048 + wid) * 16;   // batch base
        #pragma unroll
        for (int i = 0; i < 8; ++i) {
            const int r = 2 * i + half;                      // row 0..15
            const float* src = eq + (tb + r) * 128 + ((pos ^ (r & 7)) << 2);
            gload_lds16(B + i * 1024, src);
        }
    };

    STAGE(buf0, 0);

    #pragma unroll
    for (int it = 0; it < 8; ++it) {
        char* cur = (it & 1) ? buf1 : buf0;
        char* nxt = (it & 1) ? buf0 : buf1;
        if (it + 1 < 8) STAGE(nxt, it + 1);

        // wait for cur's 8 staging loads (the 8 newest outstanding = nxt's,
        // which stay in flight across compute+store); in-order vmcnt
        asm volatile("s_waitcnt vmcnt(8)" ::: "memory");
        __builtin_amdgcn_sched_barrier(0);

        // ---- frag reads (swizzled, conflict-free) + cvt + pilot ----
        short8 xfr[4];
        #pragma unroll
        for (int kk = 0; kk < 4; ++kk) {
            const int p0 = kk * 8 + q * 2;
            float4v lo = *(const float4v*)(cur + m * 512 + ((p0 ^ (m & 7)) << 4));
            float4v hi = *(const float4v*)(cur + m * 512 + (((p0 + 1) ^ (m & 7)) << 4));
            short8 f;
            #pragma unroll
            for (int j = 0; j < 8; ++j) {
                float xv = (j < 4) ? lo[j] : hi[j - 4];
                const int k = kk * 32 + q * 8 + j;
                if ((PMASK >> (k & 63)) & 1ull)
                    xv = (k < 64) ? 1.0f : 0.0f;   // pilot: real->1, imag->0
                f[j] = f2bf(xv);
            }
            xfr[kk] = f;
        }

        // ---- MFMA: Wt frags from L1/L2 (32KB, hot), weights on M side ----
        float4v acc[8];
        #pragma unroll
        for (int nt = 0; nt < 8; ++nt)
            acc[nt] = (float4v){0.f, 0.f, 0.f, 0.f};
        #pragma unroll
        for (int kk = 0; kk < 4; ++kk) {
            short8 wfr[8];
            #pragma unroll
            for (int nt = 0; nt < 8; ++nt)
                wfr[nt] = *(const short8*)(wt + (nt * 16 + m) * 128 + kk * 32 + q * 8);
            #pragma unroll
            for (int nt = 0; nt < 8; ++nt)
                acc[nt] = __builtin_amdgcn_mfma_f32_16x16x32_bf16(
                    wfr[nt], xfr[kk], acc[nt], 0, 0, 0);
        }

        // ---- out-stage into cur (input dead after cvt), same swizzle ----
        // lane (q,m): acc[nt] = out row m, floats nt*16+q*4 .. +3 => chunk nt*4+q
        #pragma unroll
        for (int nt = 0; nt < 8; ++nt) {
            const int p = nt * 4 + q;
            *(float4v*)(cur + m * 512 + ((p ^ (m & 7)) << 4)) = acc[nt];
        }

        // ---- drain: dense 1KB contiguous stores (2 rows per instr) ----
        const size_t ob = (size_t)(it * 2048 + wid) * 16 * 128;
        #pragma unroll
        for (int i = 0; i < 8; ++i) {
            const int r = 2 * i + half;
            float4v vv = *(const float4v*)(cur + r * 512 + ((pos ^ (r & 7)) << 4));
            *(float4v*)(out + ob + r * 128 + pos * 4) = vv;
        }
    }
}

extern "C" void kernel_launch(void* const* d_in, const int* in_sizes, int n_in,
                              void* d_out, int out_size, void* d_ws, size_t ws_size,
                              hipStream_t stream) {
    const float* eq   = (const float*)d_in[0];
    const float* cosk = (const float*)d_in[1];
    const float* sink = (const float*)d_in[2];
    float* out = (float*)d_out;
    short* wt  = (short*)d_ws;   // 128*128*2 = 32768 B of workspace

    hipLaunchKernelGGL(build_wt, dim3(64), dim3(256), 0, stream, cosk, sink, wt);
    // 512 blocks * 4 waves * 8 tiles * 16 batches = 262144, exact cover
    hipLaunchKernelGGL(ofdm_idft_kernel, dim3(512), dim3(256), 65536, stream,
                       eq, wt, out);
}

// Round 8
// 241.563 us; speedup vs baseline: 1.1031x; 1.1031x over previous
//
#include <hip/hip_runtime.h>

typedef __attribute__((ext_vector_type(8))) short short8;   // 8 bf16 = 4 VGPRs
typedef __attribute__((ext_vector_type(4))) float float4v;  // 4 fp32

static __device__ inline short f2bf(float f) {
    union { float f; unsigned u; } v; v.f = f;
    unsigned u = v.u;
    u += 0x7fffu + ((u >> 16) & 1u);   // round-to-nearest-even
    return (short)(u >> 16);
}

// Setup: pre-swizzled C and S tables (64x64 bf16 each) into d_ws.
// Table t element (n,k) -> short index t*4096 + n*64 + (((k>>3)^(n&7))<<3) + (k&7)
// (row n = 128B = 8 chunks of 16B; chunk c stored at c^(n&7): XOR bank swizzle,
// bijective per row, so the main kernel stages LDS linearly and reads swizzled.)
__global__ __launch_bounds__(256)
void build_wt(const float* __restrict__ cosk, const float* __restrict__ sink,
              short* __restrict__ wt)
{
    const int idx = blockIdx.x * 256 + threadIdx.x;  // 0..8191
    const int t = idx >> 12, n = (idx >> 6) & 63, k = idx & 63;
    const float v = t ? sink[n * 64 + k] : cosk[n * 64 + k];
    wt[t * 4096 + n * 64 + (((k >> 3) ^ (n & 7)) << 3) + (k & 7)] = f2bf(v);
}

// async 16B global->LDS (wave-uniform LDS base + lane*16, PER-LANE global src)
typedef __attribute__((address_space(1))) const unsigned g_u32;
typedef __attribute__((address_space(3))) unsigned l_u32;
__device__ static inline void gload_lds16(void* l, const void* g) {
    __builtin_amdgcn_global_load_lds((g_u32*)g, (l_u32*)l, 16, 0, 0);
}

// out[b][n<64]  = sum_k C[n][k]*xr[k] - S[n][k]*xi[k]
// out[b][n>=64] = sum_k S[n][k]*xr[k] + C[n][k]*xi[k]
// C,S staged ONCE into LDS per block (16KB); all weight-frag reads are
// ds_read_b128 (LDS pipe), freeing VMEM for pure streaming: per wave-tile
// only 8 input dwordx4 loads + 8 dense 1KB output stores.
// 1024 blocks x 4 waves x 4 tiles x 16 batches = 262144; each wave owns 64
// CONTIGUOUS batches (block = 512 contiguous: L2/L3-friendly like round 0).
__global__ __launch_bounds__(256, 4)
void ofdm_idft_kernel(const float* __restrict__ eq,
                      const short* __restrict__ wt,
                      float* __restrict__ out)
{
    __shared__ char wlds[16384];     // C (8KB) + S (8KB), pre-swizzled
    __shared__ char obuf[4][8192];   // per-wave out-stage, XOR-swizzled rows
    const int lane = threadIdx.x & 63;
    const int wave = threadIdx.x >> 6;
    const int m    = lane & 15;   // batch row (B/D col) & weight-row select
    const int q    = lane >> 4;   // quad: k-slice for frags, row-group for D
    const int half = lane >> 5;   // drain: row parity
    const int pos  = lane & 31;   // drain: 16B chunk within row
    const int wid  = blockIdx.x * 4 + wave;   // 0..4095

    // ---- stage C/S into LDS (linear dest = base+lane*16; per-lane src!) ----
    #pragma unroll
    for (int i = 0; i < 4; ++i)
        gload_lds16(wlds + wave * 4096 + i * 1024,
                    (const char*)wt + wave * 4096 + i * 1024 + lane * 16);
    asm volatile("s_waitcnt vmcnt(0)" ::: "memory");
    __syncthreads();

    const unsigned long long PMASK =
        (1ull << 11) | (1ull << 25) | (1ull << 39) | (1ull << 53);
    const char* Ct = wlds;
    const char* St = wlds + 8192;
    char* ob = obuf[wave];

    #pragma unroll
    for (int it = 0; it < 4; ++it) {
        const size_t tb = ((size_t)wid * 4 + it) * 16;   // batch base (contig)

        // ---- input: 8 dwordx4 per lane-row (16 batches x 512B) ----
        float4v x[8];
        const float* a = eq + (tb + m) * 128 + q * 8;
        #pragma unroll
        for (int kk = 0; kk < 4; ++kk) {
            x[kk * 2 + 0] = *(const float4v*)(a + kk * 32);
            x[kk * 2 + 1] = *(const float4v*)(a + kk * 32 + 4);
        }

        // ---- cvt + pilot: xfr[kk] = X[b=m][k = kk*32 + q*8 + j] ----
        short8 xfr[4];
        #pragma unroll
        for (int kk = 0; kk < 4; ++kk) {
            short8 f;
            #pragma unroll
            for (int j = 0; j < 8; ++j) {
                float xv = (j < 4) ? x[kk * 2][j] : x[kk * 2 + 1][j - 4];
                const int k = kk * 32 + q * 8 + j;
                if ((PMASK >> (k & 63)) & 1ull)
                    xv = (k < 64) ? 1.0f : 0.0f;   // pilot: real->1, imag->0
                f[j] = f2bf(xv);
            }
            xfr[kk] = f;
        }
        // negated imag frags (bf16 sign flip) for the -S*xi term
        short8 nx2, nx3;
        #pragma unroll
        for (int j = 0; j < 8; ++j) {
            nx2[j] = xfr[2][j] ^ (short)0x8000;
            nx3[j] = xfr[3][j] ^ (short)0x8000;
        }

        // ---- MFMA: weight frags from LDS (XOR-swizzled chunks) ----
        float4v acc[8];
        #pragma unroll
        for (int nt = 0; nt < 8; ++nt)
            acc[nt] = (float4v){0.f, 0.f, 0.f, 0.f};
        #pragma unroll
        for (int t = 0; t < 4; ++t) {
            const int row = (t * 16 + m) * 128;
            short8 Cf0 = *(const short8*)(Ct + row + (((q    ) ^ (m & 7)) << 4));
            short8 Cf1 = *(const short8*)(Ct + row + (((q + 4) ^ (m & 7)) << 4));
            short8 Sf0 = *(const short8*)(St + row + (((q    ) ^ (m & 7)) << 4));
            short8 Sf1 = *(const short8*)(St + row + (((q + 4) ^ (m & 7)) << 4));
            acc[t] = __builtin_amdgcn_mfma_f32_16x16x32_bf16(Cf0, xfr[0], acc[t], 0, 0, 0);
            acc[t] = __builtin_amdgcn_mfma_f32_16x16x32_bf16(Cf1, xfr[1], acc[t], 0, 0, 0);
            acc[t] = __builtin_amdgcn_mfma_f32_16x16x32_bf16(Sf0, nx2,    acc[t], 0, 0, 0);
            acc[t] = __builtin_amdgcn_mfma_f32_16x16x32_bf16(Sf1, nx3,    acc[t], 0, 0, 0);
            acc[t + 4] = __builtin_amdgcn_mfma_f32_16x16x32_bf16(Sf0, xfr[0], acc[t + 4], 0, 0, 0);
            acc[t + 4] = __builtin_amdgcn_mfma_f32_16x16x32_bf16(Sf1, xfr[1], acc[t + 4], 0, 0, 0);
            acc[t + 4] = __builtin_amdgcn_mfma_f32_16x16x32_bf16(Cf0, xfr[2], acc[t + 4], 0, 0, 0);
            acc[t + 4] = __builtin_amdgcn_mfma_f32_16x16x32_bf16(Cf1, xfr[3], acc[t + 4], 0, 0, 0);
        }

        // ---- out-stage: lane(q,m) acc[nt][r] = row m, col nt*16+q*4+r ----
        // chunk p = nt*4+q, stored swizzled p^(m&7)  (measured clean in r6)
        #pragma unroll
        for (int nt = 0; nt < 8; ++nt) {
            const int p = nt * 4 + q;
            *(float4v*)(ob + m * 512 + ((p ^ (m & 7)) << 4)) = acc[nt];
        }

        // ---- drain: dense 1KB contiguous stores (2 rows per instr) ----
        #pragma unroll
        for (int i = 0; i < 8; ++i) {
            const int r = 2 * i + half;
            float4v vv = *(const float4v*)(ob + r * 512 + ((pos ^ (r & 7)) << 4));
            *(float4v*)(out + (tb + r) * 128 + pos * 4) = vv;
        }
    }
}

extern "C" void kernel_launch(void* const* d_in, const int* in_sizes, int n_in,
                              void* d_out, int out_size, void* d_ws, size_t ws_size,
                              hipStream_t stream) {
    const float* eq   = (const float*)d_in[0];
    const float* cosk = (const float*)d_in[1];
    const float* sink = (const float*)d_in[2];
    float* out = (float*)d_out;
    short* wt  = (short*)d_ws;   // 2*64*64*2 = 16384 B of workspace

    hipLaunchKernelGGL(build_wt, dim3(32), dim3(256), 0, stream, cosk, sink, wt);
    // 1024 blocks * 4 waves * 4 tiles * 16 batches = 262144, exact cover
    hipLaunchKernelGGL(ofdm_idft_kernel, dim3(1024), dim3(256), 0, stream,
                       eq, wt, out);
}